// Round 20
// baseline (770.252 us; speedup 1.0000x reference)
//
#include <hip/hip_runtime.h>
#include <hip/hip_bf16.h>
#include <stdint.h>
#include <math.h>

#define EMB   2048
#define NH    16
#define HD    128
#define BATCH 4
#define SEQ   2048

typedef __bf16 bf16_t;
typedef __bf16 bf16x8 __attribute__((ext_vector_type(8)));
typedef __bf16 bf16x4 __attribute__((ext_vector_type(4)));
typedef float  f32x4  __attribute__((ext_vector_type(4)));
typedef float  f32x16 __attribute__((ext_vector_type(16)));

__device__ inline void gload_lds16(const void* g, void* l) {
  __builtin_amdgcn_global_load_lds(
      (const __attribute__((address_space(1))) uint32_t*)g,
      (__attribute__((address_space(3))) uint32_t*)l, 16, 0, 0);
}

__device__ inline uint32_t pack_bf2(float a, float b) {
  uint16_t lo = __builtin_bit_cast(uint16_t, (bf16_t)a);
  uint16_t hi = __builtin_bit_cast(uint16_t, (bf16_t)b);
  return (uint32_t)lo | ((uint32_t)hi << 16);
}

__device__ inline float ex2(float x) {
#if __has_builtin(__builtin_amdgcn_exp2f)
  return __builtin_amdgcn_exp2f(x);
#else
  float r; asm volatile("v_exp_f32 %0, %1" : "=v"(r) : "v"(x)); return r;
#endif
}

__device__ inline uint32_t sext1(uint32_t x, int b) {
  return (uint32_t)(((int32_t)(x << (31 - b))) >> 31);
}
__device__ inline float andf(float p, uint32_t m) {
  return __builtin_bit_cast(float, __builtin_bit_cast(uint32_t, p) & m);
}

// ---------------- input conversion kernels ----------------

__global__ __launch_bounds__(256) void conv_bf16(const float* __restrict__ x,
                                                 bf16_t* __restrict__ y) {
  size_t t = (size_t)blockIdx.x * 256 + threadIdx.x;
  float4 v = ((const float4*)x)[t];
  bf16x4 o;
  o[0] = (bf16_t)v.x; o[1] = (bf16_t)v.y; o[2] = (bf16_t)v.z; o[3] = (bf16_t)v.w;
  ((bf16x4*)y)[t] = o;
}

__global__ __launch_bounds__(256) void convT_w(const float* __restrict__ W,
                                               bf16_t* __restrict__ Wt) {
  __shared__ float t[32][33];
  int tx = threadIdx.x & 31, ty = threadIdx.x >> 5;
  int nb = blockIdx.x * 32, kb = blockIdx.y * 32;
#pragma unroll
  for (int i = 0; i < 4; ++i)
    t[ty + 8 * i][tx] = W[(size_t)(kb + ty + 8 * i) * EMB + nb + tx];
  __syncthreads();
#pragma unroll
  for (int i = 0; i < 4; ++i)
    Wt[(size_t)(nb + ty + 8 * i) * EMB + kb + tx] = (bf16_t)t[tx][ty + 8 * i];
}

__global__ __launch_bounds__(256) void pack_mask(const int* __restrict__ mask,
                                                 uint32_t* __restrict__ maskb) {
  int t = blockIdx.x * 256 + threadIdx.x;
  int q = t >> 6, w = t & 63;
  const int* row = mask + (size_t)q * SEQ + w * 32;
  uint32_t acc = 0;
#pragma unroll 8
  for (int i = 0; i < 32; ++i) acc |= (row[i] != 0 ? 1u : 0u) << i;
  maskb[t] = acc;
}

// ---------------- 256x256 bf16 GEMM, single-burst schedule (R14 best) -------
#define KTILES (EMB / 64)

template <int MODE>
__global__ __launch_bounds__(512, 2) void gemm256(const bf16_t* __restrict__ A,
                                                  const bf16_t* __restrict__ Bt,
                                                  bf16_t* __restrict__ outb,
                                                  float* __restrict__ outf,
                                                  const float* __restrict__ bias) {
  extern __shared__ bf16_t lds[];   // A: [2][256][64] at 0; B: same at +32768
  const int tid = threadIdx.x;
  const int wid = tid >> 6, lane = tid & 63;
  const int wr = wid >> 2;
  const int wcn = wid & 3;
  const int tn = blockIdx.x & 7;
  const int tm = blockIdx.x >> 3;
  const int m0 = tm * 256, n0 = tn * 256;

  f32x4 acc[8][4] = {};
  bf16x8 af0[4][2], af1[4][2], bfrg[4][2];

  const int trow = tid >> 3;
  const int schunk = ((tid & 7) ^ (trow & 7)) * 8;
  const int fr = lane & 15;
  const int l7 = lane & 7;
  const int hi4 = lane >> 4;
  int cslot[2];
  cslot[0] = ((hi4) ^ l7) * 8;
  cslot[1] = ((4 + hi4) ^ l7) * 8;
  const int arow = wr * 128 + fr;
  const int brow = wcn * 64 + fr;

#define STAGE_HALF(DST, SRC)                                                    \
  do {                                                                          \
    gload_lds16((SRC), &lds[(DST) + wid * 512]);                                \
    gload_lds16((SRC) + (size_t)64 * EMB, &lds[(DST) + wid * 512 + 4096]);      \
  } while (0)

#define STAGE_TILE(B, KT)                                                       \
  do {                                                                          \
    const bf16_t* _a = A + (size_t)(m0 + trow) * EMB + (KT) * 64 + schunk;      \
    STAGE_HALF((B) * 16384, _a);                                                \
    STAGE_HALF((B) * 16384 + 8192, _a + (size_t)128 * EMB);                     \
    const bf16_t* _b = Bt + (size_t)(n0 + trow) * EMB + (KT) * 64 + schunk;     \
    STAGE_HALF(32768 + (B) * 16384, _b);                                        \
    STAGE_HALF(32768 + (B) * 16384 + 8192, _b + (size_t)128 * EMB);             \
  } while (0)

#define READ_A(DST, P, QM)                                                      \
  _Pragma("unroll") for (int i = 0; i < 4; ++i)                                 \
  _Pragma("unroll") for (int ks = 0; ks < 2; ++ks)                              \
    DST[i][ks] = *(const bf16x8*)&lds[(P) * 16384 +                             \
                    (arow + ((QM) * 4 + i) * 16) * 64 + cslot[ks]];

#define READ_B_ALL(P)                                                           \
  _Pragma("unroll") for (int nf = 0; nf < 4; ++nf)                              \
  _Pragma("unroll") for (int ks = 0; ks < 2; ++ks)                              \
    bfrg[nf][ks] = *(const bf16x8*)&lds[32768 + (P) * 16384 +                   \
                    (brow + nf * 16) * 64 + cslot[ks]];

#define MFMA_HALF(SRC, QM)                                                      \
    _Pragma("unroll") for (int i = 0; i < 4; ++i)                               \
    _Pragma("unroll") for (int nf = 0; nf < 4; ++nf)                            \
    _Pragma("unroll") for (int ks = 0; ks < 2; ++ks) {                          \
      if (MODE == 1)                                                            \
        acc[(QM) * 4 + i][nf] = __builtin_amdgcn_mfma_f32_16x16x32_bf16(        \
            bfrg[nf][ks], SRC[i][ks], acc[(QM) * 4 + i][nf], 0, 0, 0);          \
      else                                                                      \
        acc[(QM) * 4 + i][nf] = __builtin_amdgcn_mfma_f32_16x16x32_bf16(        \
            SRC[i][ks], bfrg[nf][ks], acc[(QM) * 4 + i][nf], 0, 0, 0);          \
    }

#define ITER_MAIN(T, P)                                                         \
  do {                                                                          \
    READ_B_ALL(P);                                                              \
    READ_A(af0, P, 0);                                                          \
    READ_A(af1, P, 1);                                                          \
    __builtin_amdgcn_s_setprio(1);                                              \
    MFMA_HALF(af0, 0)                                                           \
    MFMA_HALF(af1, 1)                                                           \
    __builtin_amdgcn_s_setprio(0);                                              \
    asm volatile("s_barrier" ::: "memory");                                     \
    STAGE_TILE(P, (T) + 2);                                                     \
    asm volatile("s_waitcnt vmcnt(8)" ::: "memory");                            \
    asm volatile("s_barrier" ::: "memory");                                     \
  } while (0)

#define ITER_TAIL(P, LAST)                                                      \
  do {                                                                          \
    READ_B_ALL(P);                                                              \
    READ_A(af0, P, 0);                                                          \
    READ_A(af1, P, 1);                                                          \
    __builtin_amdgcn_s_setprio(1);                                              \
    MFMA_HALF(af0, 0)                                                           \
    MFMA_HALF(af1, 1)                                                           \
    __builtin_amdgcn_s_setprio(0);                                              \
    if (!(LAST)) {                                                              \
      asm volatile("s_waitcnt vmcnt(0)" ::: "memory");                          \
      asm volatile("s_barrier" ::: "memory");                                   \
    }                                                                           \
  } while (0)

  STAGE_TILE(0, 0);
  STAGE_TILE(1, 1);
  asm volatile("s_waitcnt vmcnt(8)" ::: "memory");
  asm volatile("s_barrier" ::: "memory");

  for (int t = 0; t < KTILES - 2; t += 2) {
    ITER_MAIN(t, 0);
    ITER_MAIN(t + 1, 1);
  }
  ITER_TAIL(0, 0);
  ITER_TAIL(1, 1);
#undef ITER_TAIL
#undef ITER_MAIN
#undef MFMA_HALF
#undef READ_B_ALL
#undef READ_A
#undef STAGE_TILE
#undef STAGE_HALF

  const int col0 = lane & 15;
  const int row0 = (lane >> 4) * 4;
#pragma unroll
  for (int mf = 0; mf < 8; ++mf) {
#pragma unroll
    for (int r = 0; r < 4; ++r) {
#pragma unroll
      for (int nf = 0; nf < 4; ++nf) {
        float v = acc[mf][nf][r];
        if (MODE == 1) {
          int nr = n0 + wcn * 64 + nf * 16 + row0 + r;
          int mc = m0 + wr * 128 + mf * 16 + col0;
          int b = mc >> 11, s = mc & 2047, h = nr >> 7, d = nr & 127;
          outb[((size_t)(b * NH + h) * HD + d) * SEQ + s] = (bf16_t)v;
        } else {
          int m = m0 + wr * 128 + mf * 16 + row0 + r;
          int n = n0 + wcn * 64 + nf * 16 + col0;
          if (MODE == 0) {
            int b = m >> 11, s = m & 2047, h = n >> 7, d = n & 127;
            outb[((size_t)(b * NH + h) * SEQ + s) * HD + d] = (bf16_t)v;
          } else {
            outf[(size_t)m * EMB + n] = v + bias[n];
          }
        }
      }
    }
  }
}

// ---------------- fused masked flash attention ----------------
// R16 sync skeleton (1 barrier/tile, mask-before-STAGE, full-tile-old vmcnt,
// KVBLK=64, 64 KiB dbuf, 2 blocks/CU) with per-wave work DOUBLED: each wave
// owns TWO 32-row q-subtiles (QBLK=256/block, grid 512).  Halves the number
// of sequential tile-instances -> amortizes the fixed per-tile latency/sync
// cost over 2x compute.  VGPR ~205 (audited < 256; canary = WRITE_SIZE).
__global__ __launch_bounds__(256, 2) void attn_fwd(const bf16_t* __restrict__ Q,
                                                   const bf16_t* __restrict__ K,
                                                   const bf16_t* __restrict__ Vt,
                                                   const uint32_t* __restrict__ maskb,
                                                   bf16_t* __restrict__ O) {
  __shared__ bf16_t Ks[2][64 * 128];   // [s][d], chunk slot = c ^ (s&15)
  __shared__ bf16_t Vs[2][128 * 64];   // [d][j], chunk slot = c ^ (d&7)
  const int tid = threadIdx.x;
  const int wid = tid >> 6, lane = tid & 63;
  const int ln = lane & 31, hi = lane >> 5;
  const int bid = blockIdx.x;                 // [0,512)
  const int slot = bid >> 3;                  // [0,64)
  const int bh = (bid & 7) * 8 + (slot >> 3);
  const int qt = slot & 7;
  const int b = bh >> 4, h = bh & 15;
  const int qa = qt * 256 + wid * 32 + ln;    // subtile A q-row
  const int qb = qa + 128;                    // subtile B q-row
  const float C2 = 0.08838834764831845f * 1.4426950408889634f;

  bf16x8 qfa[8], qfb[8];
  const bf16_t* qra = Q + ((size_t)bh * SEQ + qa) * HD;
  const bf16_t* qrb = Q + ((size_t)bh * SEQ + qb) * HD;
#pragma unroll
  for (int ks = 0; ks < 8; ++ks) {
    qfa[ks] = *(const bf16x8*)&qra[ks * 16 + hi * 8];
    qfb[ks] = *(const bf16x8*)&qrb[ks * 16 + hi * 8];
  }

  const bf16_t* kp[8];
  const bf16_t* vp[4];
#pragma unroll
  for (int ks = 0; ks < 8; ++ks)
    kp[ks] = &Ks[0][ln * 128 + (((2 * ks + hi) ^ (ln & 15)) * 8)];
#pragma unroll
  for (int ks = 0; ks < 4; ++ks)
    vp[ks] = &Vs[0][ln * 64 + (((2 * ks + hi) ^ (ln & 7)) * 8)];

  f32x16 oaccA[4] = {}, oaccB[4] = {};
  float mCA = -INFINITY, lA = 0.f;
  float mCB = -INFINITY, lB = 0.f;

  const size_t kbase = (size_t)bh * SEQ * HD;
  const size_t vbase = (size_t)bh * HD * SEQ;
  const uint2* mb = (const uint2*)maskb;

#define STAGE(BUF, KT)                                                          \
  do {                                                                          \
    const int _k0 = (KT) * 64;                                                  \
    _Pragma("unroll")                                                           \
    for (int j = 0; j < 4; ++j) {                                               \
      int i = wid * 4 + j;                                                      \
      { int r = i * 4 + (lane >> 4); int c = lane & 15;                         \
        gload_lds16(&K[kbase + (size_t)(_k0 + r) * HD + ((c ^ (r & 15)) * 8)],  \
                    &Ks[BUF][i * 512]); }                                       \
      { int r = i * 8 + (lane >> 3); int c = lane & 7;                          \
        gload_lds16(&Vt[vbase + (size_t)r * SEQ + _k0 + ((c ^ (r & 7)) * 8)],   \
                    &Vs[BUF][i * 512]); }                                       \
    }                                                                           \
  } while (0)

  const int NT = SEQ / 64;
  uint2 mwA_cur = mb[(size_t)qa * 32];
  uint2 mwB_cur = mb[(size_t)qb * 32];
  uint2 mwA_next, mwB_next;
  STAGE(0, 0);

  // Process one 32-row q-subtile against the staged K/V tile P.
#define SUBTILE(P, QF, OACC, MC, LR, MW)                                        \
  {                                                                             \
    f32x16 sacc0 = {}, sacc1 = {};                                              \
    __builtin_amdgcn_s_setprio(1);                                              \
    _Pragma("unroll")                                                           \
    for (int ks = 0; ks < 8; ++ks) {                                            \
      bf16x8 kf0 = *(const bf16x8*)(kp[ks] + (P) * 8192);                       \
      bf16x8 kf1 = *(const bf16x8*)(kp[ks] + 4096 + (P) * 8192);                \
      sacc0 = __builtin_amdgcn_mfma_f32_32x32x16_bf16(kf0, QF[ks], sacc0, 0, 0, 0); \
      sacc1 = __builtin_amdgcn_mfma_f32_32x32x16_bf16(kf1, QF[ks], sacc1, 0, 0, 0); \
    }                                                                           \
    __builtin_amdgcn_s_setprio(0);                                              \
    const uint32_t mwx = (MW).x >> (4 * hi);                                    \
    const uint32_t mwy = (MW).y >> (4 * hi);                                    \
    float pmax = -INFINITY;                                                     \
    _Pragma("unroll")                                                           \
    for (int r = 0; r < 16; r += 4)                                             \
      pmax = fmaxf(pmax, fmaxf(fmaxf(sacc0[r], sacc0[r + 1]),                   \
                               fmaxf(sacc0[r + 2], sacc0[r + 3])));             \
    _Pragma("unroll")                                                           \
    for (int r = 0; r < 16; r += 4)                                             \
      pmax = fmaxf(pmax, fmaxf(fmaxf(sacc1[r], sacc1[r + 1]),                   \
                               fmaxf(sacc1[r + 2], sacc1[r + 3])));             \
    pmax = fmaxf(pmax, __shfl_xor(pmax, 32, 64));                               \
    const float pmaxC = pmax * C2;                                              \
    if (!__all(pmaxC - (MC) <= 8.0f)) {                                         \
      const float mnewC = fmaxf((MC), pmaxC);                                   \
      const float corr = ex2((MC) - mnewC);                                     \
      _Pragma("unroll")                                                         \
      for (int mv = 0; mv < 4; ++mv)                                            \
        _Pragma("unroll")                                                       \
        for (int r = 0; r < 16; ++r) OACC[mv][r] *= corr;                       \
      (LR) *= corr;                                                             \
      (MC) = mnewC;                                                             \
    }                                                                           \
    const float nmC = -(MC);                                                    \
    float psum = 0.f;                                                           \
    uint32_t pk[2][4][2];                                                       \
    _Pragma("unroll")                                                           \
    for (int g = 0; g < 4; ++g) {                                               \
      float p0 = andf(ex2(fmaf(sacc0[4 * g + 0], C2, nmC)), sext1(mwx, 8 * g + 0)); \
      float p1 = andf(ex2(fmaf(sacc0[4 * g + 1], C2, nmC)), sext1(mwx, 8 * g + 1)); \
      float p2 = andf(ex2(fmaf(sacc0[4 * g + 2], C2, nmC)), sext1(mwx, 8 * g + 2)); \
      float p3 = andf(ex2(fmaf(sacc0[4 * g + 3], C2, nmC)), sext1(mwx, 8 * g + 3)); \
      psum += (p0 + p1) + (p2 + p3);                                            \
      pk[0][g][0] = pack_bf2(p0, p1);                                           \
      pk[0][g][1] = pack_bf2(p2, p3);                                           \
      float q0 = andf(ex2(fmaf(sacc1[4 * g + 0], C2, nmC)), sext1(mwy, 8 * g + 0)); \
      float q1 = andf(ex2(fmaf(sacc1[4 * g + 1], C2, nmC)), sext1(mwy, 8 * g + 1)); \
      float q2 = andf(ex2(fmaf(sacc1[4 * g + 2], C2, nmC)), sext1(mwy, 8 * g + 2)); \
      float q3 = andf(ex2(fmaf(sacc1[4 * g + 3], C2, nmC)), sext1(mwy, 8 * g + 3)); \
      psum += (q0 + q1) + (q2 + q3);                                            \
      pk[1][g][0] = pack_bf2(q0, q1);                                           \
      pk[1][g][1] = pack_bf2(q2, q3);                                           \
    }                                                                           \
    psum += __shfl_xor(psum, 32, 64);                                           \
    (LR) += psum;                                                               \
    _Pragma("unroll")                                                           \
    for (int ks = 0; ks < 4; ++ks) {                                            \
      const int mfp = ks >> 1;                                                  \
      const int gA = (2 * ks) & 3;                                              \
      uint32_t w0 = pk[mfp][gA][0], w1 = pk[mfp][gA][1];                        \
      uint32_t w2 = pk[mfp][gA + 1][0], w3 = pk[mfp][gA + 1][1];                \
      asm("v_permlane32_swap_b32 %0, %1" : "+v"(w0), "+v"(w2));                 \
      asm("v_permlane32_swap_b32 %0, %1" : "+v"(w1), "+v"(w3));                 \
      uint4 bw = make_uint4(w0, w1, w2, w3);                                    \
      bf16x8 pb = __builtin_bit_cast(bf16x8, bw);                               \
      __builtin_amdgcn_s_setprio(1);                                            \
      _Pragma("unroll")                                                         \
      for (int mv = 0; mv < 4; ++mv) {                                          \
        bf16x8 vf = *(const bf16x8*)(vp[ks] + mv * 2048 + (P) * 8192);          \
        OACC[mv] = __builtin_amdgcn_mfma_f32_32x32x16_bf16(vf, pb, OACC[mv], 0, 0, 0); \
      }                                                                         \
      __builtin_amdgcn_s_setprio(0);                                            \
    }                                                                           \
  }

#define TILE(KT, P)                                                             \
  {                                                                             \
    asm volatile("s_waitcnt vmcnt(0)" ::: "memory");                            \
    asm volatile("s_barrier" ::: "memory");                                     \
    if ((KT) + 1 < NT) {                                                        \
      mwA_next = mb[(size_t)qa * 32 + (KT) + 1];                                \
      mwB_next = mb[(size_t)qb * 32 + (KT) + 1];                                \
      STAGE((P) ^ 1, (KT) + 1);                                                 \
    }                                                                           \
    SUBTILE(P, qfa, oaccA, mCA, lA, mwA_cur)                                    \
    SUBTILE(P, qfb, oaccB, mCB, lB, mwB_cur)                                    \
    mwA_cur = mwA_next;                                                         \
    mwB_cur = mwB_next;                                                         \
  }

  for (int t = 0; t < NT; t += 2) {
    TILE(t, 0);
    TILE(t + 1, 1);
  }
#undef TILE
#undef SUBTILE
#undef STAGE

  const float invlA = 1.f / lA;
  const float invlB = 1.f / lB;
  bf16_t* orowA = O + ((size_t)b * SEQ + qa) * EMB + h * HD;
  bf16_t* orowB = O + ((size_t)b * SEQ + qb) * EMB + h * HD;
#pragma unroll
  for (int mv = 0; mv < 4; ++mv) {
#pragma unroll
    for (int g = 0; g < 4; ++g) {
      int d = mv * 32 + 8 * g + 4 * hi;
      bf16x4 ova, ovb;
      ova[0] = (bf16_t)(oaccA[mv][4 * g + 0] * invlA);
      ova[1] = (bf16_t)(oaccA[mv][4 * g + 1] * invlA);
      ova[2] = (bf16_t)(oaccA[mv][4 * g + 2] * invlA);
      ova[3] = (bf16_t)(oaccA[mv][4 * g + 3] * invlA);
      *(bf16x4*)&orowA[d] = ova;
      ovb[0] = (bf16_t)(oaccB[mv][4 * g + 0] * invlB);
      ovb[1] = (bf16_t)(oaccB[mv][4 * g + 1] * invlB);
      ovb[2] = (bf16_t)(oaccB[mv][4 * g + 2] * invlB);
      ovb[3] = (bf16_t)(oaccB[mv][4 * g + 3] * invlB);
      *(bf16x4*)&orowB[d] = ovb;
    }
  }
}

// ---------------- host launch ----------------

extern "C" void kernel_launch(void* const* d_in, const int* in_sizes, int n_in,
                              void* d_out, int out_size, void* d_ws, size_t ws_size,
                              hipStream_t stream) {
  const float* values = (const float*)d_in[0];
  const float* keys   = (const float*)d_in[1];
  const float* query  = (const float*)d_in[2];
  const int*   mask   = (const int*)d_in[3];
  const float* Wv = (const float*)d_in[4];
  const float* Wk = (const float*)d_in[5];
  const float* Wq = (const float*)d_in[6];
  const float* Wo = (const float*)d_in[7];
  const float* bo = (const float*)d_in[8];
  float* out = (float*)d_out;

  char* ws = (char*)d_ws;
  bf16_t*   Xbuf  = (bf16_t*)(ws);                 // 8192x2048 bf16, reused for O
  bf16_t*   Wbuf  = (bf16_t*)(ws + 33554432);      // 2048x2048 bf16
  bf16_t*   Qb    = (bf16_t*)(ws + 41943040);      // [B][H][S][D]
  bf16_t*   Kb    = (bf16_t*)(ws + 75497472);      // [B][H][S][D]
  bf16_t*   Vtb   = (bf16_t*)(ws + 109051904);     // [B][H][D][S]
  uint32_t* maskb = (uint32_t*)(ws + 142606336);   // [S][64]

  static const size_t GEMM_LDS = 131072;
  hipFuncSetAttribute(reinterpret_cast<const void*>(gemm256<0>),
                      hipFuncAttributeMaxDynamicSharedMemorySize, (int)GEMM_LDS);
  hipFuncSetAttribute(reinterpret_cast<const void*>(gemm256<1>),
                      hipFuncAttributeMaxDynamicSharedMemorySize, (int)GEMM_LDS);
  hipFuncSetAttribute(reinterpret_cast<const void*>(gemm256<2>),
                      hipFuncAttributeMaxDynamicSharedMemorySize, (int)GEMM_LDS);

  dim3 b256(256), b512(512);
  dim3 gconv(16384);
  dim3 gw(64, 64);
  dim3 gg(256);          // 32 m-tiles x 8 n-tiles; tn = bid&7 (XCD-aligned)
  dim3 ga(512);          // 8 q-tiles x 64 bh, XCD-swizzled (QBLK=256)

  pack_mask<<<dim3(512), b256, 0, stream>>>(mask, maskb);

  conv_bf16<<<gconv, b256, 0, stream>>>(query, Xbuf);
  convT_w<<<gw, b256, 0, stream>>>(Wq, Wbuf);
  gemm256<0><<<gg, b512, GEMM_LDS, stream>>>(Xbuf, Wbuf, Qb, nullptr, nullptr);

  conv_bf16<<<gconv, b256, 0, stream>>>(keys, Xbuf);
  convT_w<<<gw, b256, 0, stream>>>(Wk, Wbuf);
  gemm256<0><<<gg, b512, GEMM_LDS, stream>>>(Xbuf, Wbuf, Kb, nullptr, nullptr);

  conv_bf16<<<gconv, b256, 0, stream>>>(values, Xbuf);
  convT_w<<<gw, b256, 0, stream>>>(Wv, Wbuf);
  gemm256<1><<<gg, b512, GEMM_LDS, stream>>>(Xbuf, Wbuf, Vtb, nullptr, nullptr);

  attn_fwd<<<ga, b256, 0, stream>>>(Qb, Kb, Vtb, maskb, Xbuf);

  convT_w<<<gw, b256, 0, stream>>>(Wo, Wbuf);
  gemm256<2><<<gg, b512, GEMM_LDS, stream>>>(Xbuf, Wbuf, nullptr, out, bo);
}

// Round 21
// 525.733 us; speedup vs baseline: 1.4651x; 1.4651x over previous
//
#include <hip/hip_runtime.h>
#include <hip/hip_bf16.h>
#include <stdint.h>
#include <math.h>

#define EMB   2048
#define NH    16
#define HD    128
#define BATCH 4
#define SEQ   2048

typedef __bf16 bf16_t;
typedef __bf16 bf16x8 __attribute__((ext_vector_type(8)));
typedef __bf16 bf16x4 __attribute__((ext_vector_type(4)));
typedef float  f32x4  __attribute__((ext_vector_type(4)));
typedef float  f32x16 __attribute__((ext_vector_type(16)));

__device__ inline void gload_lds16(const void* g, void* l) {
  __builtin_amdgcn_global_load_lds(
      (const __attribute__((address_space(1))) uint32_t*)g,
      (__attribute__((address_space(3))) uint32_t*)l, 16, 0, 0);
}

__device__ inline uint32_t pack_bf2(float a, float b) {
  uint16_t lo = __builtin_bit_cast(uint16_t, (bf16_t)a);
  uint16_t hi = __builtin_bit_cast(uint16_t, (bf16_t)b);
  return (uint32_t)lo | ((uint32_t)hi << 16);
}

__device__ inline float ex2(float x) {
#if __has_builtin(__builtin_amdgcn_exp2f)
  return __builtin_amdgcn_exp2f(x);
#else
  float r; asm volatile("v_exp_f32 %0, %1" : "=v"(r) : "v"(x)); return r;
#endif
}

__device__ inline uint32_t sext1(uint32_t x, int b) {
  return (uint32_t)(((int32_t)(x << (31 - b))) >> 31);
}
__device__ inline float andf(float p, uint32_t m) {
  return __builtin_bit_cast(float, __builtin_bit_cast(uint32_t, p) & m);
}

// ---------------- input conversion kernels ----------------

__global__ __launch_bounds__(256) void conv_bf16(const float* __restrict__ x,
                                                 bf16_t* __restrict__ y) {
  size_t t = (size_t)blockIdx.x * 256 + threadIdx.x;
  float4 v = ((const float4*)x)[t];
  bf16x4 o;
  o[0] = (bf16_t)v.x; o[1] = (bf16_t)v.y; o[2] = (bf16_t)v.z; o[3] = (bf16_t)v.w;
  ((bf16x4*)y)[t] = o;
}

__global__ __launch_bounds__(256) void convT_w(const float* __restrict__ W,
                                               bf16_t* __restrict__ Wt) {
  __shared__ float t[32][33];
  int tx = threadIdx.x & 31, ty = threadIdx.x >> 5;
  int nb = blockIdx.x * 32, kb = blockIdx.y * 32;
#pragma unroll
  for (int i = 0; i < 4; ++i)
    t[ty + 8 * i][tx] = W[(size_t)(kb + ty + 8 * i) * EMB + nb + tx];
  __syncthreads();
#pragma unroll
  for (int i = 0; i < 4; ++i)
    Wt[(size_t)(nb + ty + 8 * i) * EMB + kb + tx] = (bf16_t)t[tx][ty + 8 * i];
}

__global__ __launch_bounds__(256) void pack_mask(const int* __restrict__ mask,
                                                 uint32_t* __restrict__ maskb) {
  int t = blockIdx.x * 256 + threadIdx.x;
  int q = t >> 6, w = t & 63;
  const int* row = mask + (size_t)q * SEQ + w * 32;
  uint32_t acc = 0;
#pragma unroll 8
  for (int i = 0; i < 32; ++i) acc |= (row[i] != 0 ? 1u : 0u) << i;
  maskb[t] = acc;
}

// ---------------- 256x256 bf16 GEMM, single-burst schedule (R14 best) -------
#define KTILES (EMB / 64)

template <int MODE>
__global__ __launch_bounds__(512, 2) void gemm256(const bf16_t* __restrict__ A,
                                                  const bf16_t* __restrict__ Bt,
                                                  bf16_t* __restrict__ outb,
                                                  float* __restrict__ outf,
                                                  const float* __restrict__ bias) {
  extern __shared__ bf16_t lds[];   // A: [2][256][64] at 0; B: same at +32768
  const int tid = threadIdx.x;
  const int wid = tid >> 6, lane = tid & 63;
  const int wr = wid >> 2;
  const int wcn = wid & 3;
  const int tn = blockIdx.x & 7;
  const int tm = blockIdx.x >> 3;
  const int m0 = tm * 256, n0 = tn * 256;

  f32x4 acc[8][4] = {};
  bf16x8 af0[4][2], af1[4][2], bfrg[4][2];

  const int trow = tid >> 3;
  const int schunk = ((tid & 7) ^ (trow & 7)) * 8;
  const int fr = lane & 15;
  const int l7 = lane & 7;
  const int hi4 = lane >> 4;
  int cslot[2];
  cslot[0] = ((hi4) ^ l7) * 8;
  cslot[1] = ((4 + hi4) ^ l7) * 8;
  const int arow = wr * 128 + fr;
  const int brow = wcn * 64 + fr;

#define STAGE_HALF(DST, SRC)                                                    \
  do {                                                                          \
    gload_lds16((SRC), &lds[(DST) + wid * 512]);                                \
    gload_lds16((SRC) + (size_t)64 * EMB, &lds[(DST) + wid * 512 + 4096]);      \
  } while (0)

#define STAGE_TILE(B, KT)                                                       \
  do {                                                                          \
    const bf16_t* _a = A + (size_t)(m0 + trow) * EMB + (KT) * 64 + schunk;      \
    STAGE_HALF((B) * 16384, _a);                                                \
    STAGE_HALF((B) * 16384 + 8192, _a + (size_t)128 * EMB);                     \
    const bf16_t* _b = Bt + (size_t)(n0 + trow) * EMB + (KT) * 64 + schunk;     \
    STAGE_HALF(32768 + (B) * 16384, _b);                                        \
    STAGE_HALF(32768 + (B) * 16384 + 8192, _b + (size_t)128 * EMB);             \
  } while (0)

#define READ_A(DST, P, QM)                                                      \
  _Pragma("unroll") for (int i = 0; i < 4; ++i)                                 \
  _Pragma("unroll") for (int ks = 0; ks < 2; ++ks)                              \
    DST[i][ks] = *(const bf16x8*)&lds[(P) * 16384 +                             \
                    (arow + ((QM) * 4 + i) * 16) * 64 + cslot[ks]];

#define READ_B_ALL(P)                                                           \
  _Pragma("unroll") for (int nf = 0; nf < 4; ++nf)                              \
  _Pragma("unroll") for (int ks = 0; ks < 2; ++ks)                              \
    bfrg[nf][ks] = *(const bf16x8*)&lds[32768 + (P) * 16384 +                   \
                    (brow + nf * 16) * 64 + cslot[ks]];

#define MFMA_HALF(SRC, QM)                                                      \
    _Pragma("unroll") for (int i = 0; i < 4; ++i)                               \
    _Pragma("unroll") for (int nf = 0; nf < 4; ++nf)                            \
    _Pragma("unroll") for (int ks = 0; ks < 2; ++ks) {                          \
      if (MODE == 1)                                                            \
        acc[(QM) * 4 + i][nf] = __builtin_amdgcn_mfma_f32_16x16x32_bf16(        \
            bfrg[nf][ks], SRC[i][ks], acc[(QM) * 4 + i][nf], 0, 0, 0);          \
      else                                                                      \
        acc[(QM) * 4 + i][nf] = __builtin_amdgcn_mfma_f32_16x16x32_bf16(        \
            SRC[i][ks], bfrg[nf][ks], acc[(QM) * 4 + i][nf], 0, 0, 0);          \
    }

#define ITER_MAIN(T, P)                                                         \
  do {                                                                          \
    READ_B_ALL(P);                                                              \
    READ_A(af0, P, 0);                                                          \
    READ_A(af1, P, 1);                                                          \
    __builtin_amdgcn_s_setprio(1);                                              \
    MFMA_HALF(af0, 0)                                                           \
    MFMA_HALF(af1, 1)                                                           \
    __builtin_amdgcn_s_setprio(0);                                              \
    asm volatile("s_barrier" ::: "memory");                                     \
    STAGE_TILE(P, (T) + 2);                                                     \
    asm volatile("s_waitcnt vmcnt(8)" ::: "memory");                            \
    asm volatile("s_barrier" ::: "memory");                                     \
  } while (0)

#define ITER_TAIL(P, LAST)                                                      \
  do {                                                                          \
    READ_B_ALL(P);                                                              \
    READ_A(af0, P, 0);                                                          \
    READ_A(af1, P, 1);                                                          \
    __builtin_amdgcn_s_setprio(1);                                              \
    MFMA_HALF(af0, 0)                                                           \
    MFMA_HALF(af1, 1)                                                           \
    __builtin_amdgcn_s_setprio(0);                                              \
    if (!(LAST)) {                                                              \
      asm volatile("s_waitcnt vmcnt(0)" ::: "memory");                          \
      asm volatile("s_barrier" ::: "memory");                                   \
    }                                                                           \
  } while (0)

  STAGE_TILE(0, 0);
  STAGE_TILE(1, 1);
  asm volatile("s_waitcnt vmcnt(8)" ::: "memory");
  asm volatile("s_barrier" ::: "memory");

  for (int t = 0; t < KTILES - 2; t += 2) {
    ITER_MAIN(t, 0);
    ITER_MAIN(t + 1, 1);
  }
  ITER_TAIL(0, 0);
  ITER_TAIL(1, 1);
#undef ITER_TAIL
#undef ITER_MAIN
#undef MFMA_HALF
#undef READ_B_ALL
#undef READ_A
#undef STAGE_TILE
#undef STAGE_HALF

  const int col0 = lane & 15;
  const int row0 = (lane >> 4) * 4;
#pragma unroll
  for (int mf = 0; mf < 8; ++mf) {
#pragma unroll
    for (int r = 0; r < 4; ++r) {
#pragma unroll
      for (int nf = 0; nf < 4; ++nf) {
        float v = acc[mf][nf][r];
        if (MODE == 1) {
          int nr = n0 + wcn * 64 + nf * 16 + row0 + r;
          int mc = m0 + wr * 128 + mf * 16 + col0;
          int b = mc >> 11, s = mc & 2047, h = nr >> 7, d = nr & 127;
          outb[((size_t)(b * NH + h) * HD + d) * SEQ + s] = (bf16_t)v;
        } else {
          int m = m0 + wr * 128 + mf * 16 + row0 + r;
          int n = n0 + wcn * 64 + nf * 16 + col0;
          if (MODE == 0) {
            int b = m >> 11, s = m & 2047, h = n >> 7, d = n & 127;
            outb[((size_t)(b * NH + h) * SEQ + s) * HD + d] = (bf16_t)v;
          } else {
            outf[(size_t)m * EMB + n] = v + bias[n];
          }
        }
      }
    }
  }
}

// ---------------- fused masked flash attention (R16 best: 203 us) -----------
// 4 waves x 32 q-rows, KVBLK=64, K+V double-buffer (64 KiB, 2 blocks/CU).
// One barrier/tile; mask prefetched BEFORE STAGE; vmcnt(0) waits loads issued
// a full tile earlier.  K chunk swizzle c^(r&15) (2-way, free); V c^(r&7).
// Swapped-operand MFMA; pair-reduce max/sum via ^32 shfl; post-exp sign-mask;
// permlane32_swap PV exchange.
__global__ __launch_bounds__(256, 2) void attn_fwd(const bf16_t* __restrict__ Q,
                                                   const bf16_t* __restrict__ K,
                                                   const bf16_t* __restrict__ Vt,
                                                   const uint32_t* __restrict__ maskb,
                                                   bf16_t* __restrict__ O) {
  __shared__ bf16_t Ks[2][64 * 128];   // [s][d], chunk slot = c ^ (s&15)
  __shared__ bf16_t Vs[2][128 * 64];   // [d][j], chunk slot = c ^ (d&7)
  const int tid = threadIdx.x;
  const int wid = tid >> 6, lane = tid & 63;
  const int ln = lane & 31, hi = lane >> 5;
  const int bid = blockIdx.x;
  const int slot = bid >> 3;
  const int bh = (bid & 7) * 8 + (slot >> 4);
  const int qt = slot & 15;
  const int b = bh >> 4, h = bh & 15;
  const int q = qt * 128 + wid * 32 + ln;
  const float C2 = 0.08838834764831845f * 1.4426950408889634f;

  bf16x8 qf[8];
  const bf16_t* qrow = Q + ((size_t)bh * SEQ + q) * HD;
#pragma unroll
  for (int ks = 0; ks < 8; ++ks)
    qf[ks] = *(const bf16x8*)&qrow[ks * 16 + hi * 8];

  const bf16_t* kp[8];
  const bf16_t* vp[4];
#pragma unroll
  for (int ks = 0; ks < 8; ++ks)
    kp[ks] = &Ks[0][ln * 128 + (((2 * ks + hi) ^ (ln & 15)) * 8)];
#pragma unroll
  for (int ks = 0; ks < 4; ++ks)
    vp[ks] = &Vs[0][ln * 64 + (((2 * ks + hi) ^ (ln & 7)) * 8)];

  f32x16 oacc[4] = {};
  float mC = -INFINITY, l_run = 0.f;

  const size_t kbase = (size_t)bh * SEQ * HD;
  const size_t vbase = (size_t)bh * HD * SEQ;
  const uint2* mb = (const uint2*)maskb;

#define STAGE(BUF, KT)                                                          \
  do {                                                                          \
    const int _k0 = (KT) * 64;                                                  \
    _Pragma("unroll")                                                           \
    for (int j = 0; j < 4; ++j) {                                               \
      int i = wid * 4 + j;                                                      \
      { int r = i * 4 + (lane >> 4); int c = lane & 15;                         \
        gload_lds16(&K[kbase + (size_t)(_k0 + r) * HD + ((c ^ (r & 15)) * 8)],  \
                    &Ks[BUF][i * 512]); }                                       \
      { int r = i * 8 + (lane >> 3); int c = lane & 7;                          \
        gload_lds16(&Vt[vbase + (size_t)r * SEQ + _k0 + ((c ^ (r & 7)) * 8)],   \
                    &Vs[BUF][i * 512]); }                                       \
    }                                                                           \
  } while (0)

  const int NT = SEQ / 64;
  uint2 mw_cur = mb[(size_t)q * 32];
  uint2 mw_next;
  STAGE(0, 0);

#define TILE(KT, P)                                                             \
  {                                                                             \
    asm volatile("s_waitcnt vmcnt(0)" ::: "memory");                            \
    asm volatile("s_barrier" ::: "memory");                                     \
    if ((KT) + 1 < NT) {                                                        \
      mw_next = mb[(size_t)q * 32 + (KT) + 1];                                  \
      STAGE((P) ^ 1, (KT) + 1);                                                 \
    }                                                                           \
    f32x16 sacc0 = {}, sacc1 = {};                                              \
    __builtin_amdgcn_s_setprio(1);                                              \
    _Pragma("unroll")                                                           \
    for (int ks = 0; ks < 8; ++ks) {                                            \
      bf16x8 kf0 = *(const bf16x8*)(kp[ks] + (P) * 8192);                       \
      bf16x8 kf1 = *(const bf16x8*)(kp[ks] + 4096 + (P) * 8192);                \
      sacc0 = __builtin_amdgcn_mfma_f32_32x32x16_bf16(kf0, qf[ks], sacc0, 0, 0, 0); \
      sacc1 = __builtin_amdgcn_mfma_f32_32x32x16_bf16(kf1, qf[ks], sacc1, 0, 0, 0); \
    }                                                                           \
    __builtin_amdgcn_s_setprio(0);                                              \
    const uint32_t mwx = mw_cur.x >> (4 * hi);                                  \
    const uint32_t mwy = mw_cur.y >> (4 * hi);                                  \
    float pmax = -INFINITY;                                                     \
    _Pragma("unroll")                                                           \
    for (int r = 0; r < 16; r += 4)                                             \
      pmax = fmaxf(pmax, fmaxf(fmaxf(sacc0[r], sacc0[r + 1]),                   \
                               fmaxf(sacc0[r + 2], sacc0[r + 3])));             \
    _Pragma("unroll")                                                           \
    for (int r = 0; r < 16; r += 4)                                             \
      pmax = fmaxf(pmax, fmaxf(fmaxf(sacc1[r], sacc1[r + 1]),                   \
                               fmaxf(sacc1[r + 2], sacc1[r + 3])));             \
    pmax = fmaxf(pmax, __shfl_xor(pmax, 32, 64));                               \
    const float pmaxC = pmax * C2;                                              \
    if (!__all(pmaxC - mC <= 8.0f)) {                                           \
      const float mnewC = fmaxf(mC, pmaxC);                                     \
      const float corr = ex2(mC - mnewC);                                       \
      _Pragma("unroll")                                                         \
      for (int mv = 0; mv < 4; ++mv)                                            \
        _Pragma("unroll")                                                       \
        for (int r = 0; r < 16; ++r) oacc[mv][r] *= corr;                       \
      l_run *= corr;                                                            \
      mC = mnewC;                                                               \
    }                                                                           \
    const float nmC = -mC;                                                      \
    float psum = 0.f;                                                           \
    uint32_t pk[2][4][2];                                                       \
    _Pragma("unroll")                                                           \
    for (int g = 0; g < 4; ++g) {                                               \
      float p0 = andf(ex2(fmaf(sacc0[4 * g + 0], C2, nmC)), sext1(mwx, 8 * g + 0)); \
      float p1 = andf(ex2(fmaf(sacc0[4 * g + 1], C2, nmC)), sext1(mwx, 8 * g + 1)); \
      float p2 = andf(ex2(fmaf(sacc0[4 * g + 2], C2, nmC)), sext1(mwx, 8 * g + 2)); \
      float p3 = andf(ex2(fmaf(sacc0[4 * g + 3], C2, nmC)), sext1(mwx, 8 * g + 3)); \
      psum += (p0 + p1) + (p2 + p3);                                            \
      pk[0][g][0] = pack_bf2(p0, p1);                                           \
      pk[0][g][1] = pack_bf2(p2, p3);                                           \
      float q0 = andf(ex2(fmaf(sacc1[4 * g + 0], C2, nmC)), sext1(mwy, 8 * g + 0)); \
      float q1 = andf(ex2(fmaf(sacc1[4 * g + 1], C2, nmC)), sext1(mwy, 8 * g + 1)); \
      float q2 = andf(ex2(fmaf(sacc1[4 * g + 2], C2, nmC)), sext1(mwy, 8 * g + 2)); \
      float q3 = andf(ex2(fmaf(sacc1[4 * g + 3], C2, nmC)), sext1(mwy, 8 * g + 3)); \
      psum += (q0 + q1) + (q2 + q3);                                            \
      pk[1][g][0] = pack_bf2(q0, q1);                                           \
      pk[1][g][1] = pack_bf2(q2, q3);                                           \
    }                                                                           \
    psum += __shfl_xor(psum, 32, 64);                                           \
    l_run += psum;                                                              \
    _Pragma("unroll")                                                           \
    for (int ks = 0; ks < 4; ++ks) {                                            \
      const int mfp = ks >> 1;                                                  \
      const int gA = (2 * ks) & 3;                                              \
      uint32_t w0 = pk[mfp][gA][0], w1 = pk[mfp][gA][1];                        \
      uint32_t w2 = pk[mfp][gA + 1][0], w3 = pk[mfp][gA + 1][1];                \
      asm("v_permlane32_swap_b32 %0, %1" : "+v"(w0), "+v"(w2));                 \
      asm("v_permlane32_swap_b32 %0, %1" : "+v"(w1), "+v"(w3));                 \
      uint4 bw = make_uint4(w0, w1, w2, w3);                                    \
      bf16x8 pb = __builtin_bit_cast(bf16x8, bw);                               \
      __builtin_amdgcn_s_setprio(1);                                            \
      _Pragma("unroll")                                                         \
      for (int mv = 0; mv < 4; ++mv) {                                          \
        bf16x8 vf = *(const bf16x8*)(vp[ks] + mv * 2048 + (P) * 8192);          \
        oacc[mv] = __builtin_amdgcn_mfma_f32_32x32x16_bf16(vf, pb, oacc[mv], 0, 0, 0); \
      }                                                                         \
      __builtin_amdgcn_s_setprio(0);                                            \
    }                                                                           \
    mw_cur = mw_next;                                                           \
  }

  for (int t = 0; t < NT; t += 2) {
    TILE(t, 0);
    TILE(t + 1, 1);
  }
#undef TILE
#undef STAGE

  const float invl = 1.f / l_run;
  bf16_t* orow = O + ((size_t)b * SEQ + q) * EMB + h * HD;
#pragma unroll
  for (int mv = 0; mv < 4; ++mv) {
#pragma unroll
    for (int g = 0; g < 4; ++g) {
      int d = mv * 32 + 8 * g + 4 * hi;
      bf16x4 ov;
      ov[0] = (bf16_t)(oacc[mv][4 * g + 0] * invl);
      ov[1] = (bf16_t)(oacc[mv][4 * g + 1] * invl);
      ov[2] = (bf16_t)(oacc[mv][4 * g + 2] * invl);
      ov[3] = (bf16_t)(oacc[mv][4 * g + 3] * invl);
      *(bf16x4*)&orow[d] = ov;
    }
  }
}

// ---------------- host launch ----------------

extern "C" void kernel_launch(void* const* d_in, const int* in_sizes, int n_in,
                              void* d_out, int out_size, void* d_ws, size_t ws_size,
                              hipStream_t stream) {
  const float* values = (const float*)d_in[0];
  const float* keys   = (const float*)d_in[1];
  const float* query  = (const float*)d_in[2];
  const int*   mask   = (const int*)d_in[3];
  const float* Wv = (const float*)d_in[4];
  const float* Wk = (const float*)d_in[5];
  const float* Wq = (const float*)d_in[6];
  const float* Wo = (const float*)d_in[7];
  const float* bo = (const float*)d_in[8];
  float* out = (float*)d_out;

  char* ws = (char*)d_ws;
  bf16_t*   Xbuf  = (bf16_t*)(ws);                 // 8192x2048 bf16, reused for O
  bf16_t*   Wbuf  = (bf16_t*)(ws + 33554432);      // 2048x2048 bf16
  bf16_t*   Qb    = (bf16_t*)(ws + 41943040);      // [B][H][S][D]
  bf16_t*   Kb    = (bf16_t*)(ws + 75497472);      // [B][H][S][D]
  bf16_t*   Vtb   = (bf16_t*)(ws + 109051904);     // [B][H][D][S]
  uint32_t* maskb = (uint32_t*)(ws + 142606336);   // [S][64]

  static const size_t GEMM_LDS = 131072;
  hipFuncSetAttribute(reinterpret_cast<const void*>(gemm256<0>),
                      hipFuncAttributeMaxDynamicSharedMemorySize, (int)GEMM_LDS);
  hipFuncSetAttribute(reinterpret_cast<const void*>(gemm256<1>),
                      hipFuncAttributeMaxDynamicSharedMemorySize, (int)GEMM_LDS);
  hipFuncSetAttribute(reinterpret_cast<const void*>(gemm256<2>),
                      hipFuncAttributeMaxDynamicSharedMemorySize, (int)GEMM_LDS);

  dim3 b256(256), b512(512);
  dim3 gconv(16384);
  dim3 gw(64, 64);
  dim3 gg(256);          // 32 m-tiles x 8 n-tiles; tn = bid&7 (XCD-aligned)
  dim3 ga(1024);         // XCD-swizzled 1D grid: 16 q-tiles x 64 bh

  pack_mask<<<dim3(512), b256, 0, stream>>>(mask, maskb);

  conv_bf16<<<gconv, b256, 0, stream>>>(query, Xbuf);
  convT_w<<<gw, b256, 0, stream>>>(Wq, Wbuf);
  gemm256<0><<<gg, b512, GEMM_LDS, stream>>>(Xbuf, Wbuf, Qb, nullptr, nullptr);

  conv_bf16<<<gconv, b256, 0, stream>>>(keys, Xbuf);
  convT_w<<<gw, b256, 0, stream>>>(Wk, Wbuf);
  gemm256<0><<<gg, b512, GEMM_LDS, stream>>>(Xbuf, Wbuf, Kb, nullptr, nullptr);

  conv_bf16<<<gconv, b256, 0, stream>>>(values, Xbuf);
  convT_w<<<gw, b256, 0, stream>>>(Wv, Wbuf);
  gemm256<1><<<gg, b512, GEMM_LDS, stream>>>(Xbuf, Wbuf, Vtb, nullptr, nullptr);

  attn_fwd<<<ga, b256, 0, stream>>>(Qb, Kb, Vtb, maskb, Xbuf);

  convT_w<<<gw, b256, 0, stream>>>(Wo, Wbuf);
  gemm256<2><<<gg, b512, GEMM_LDS, stream>>>(Xbuf, Wbuf, nullptr, out, bo);
}